// Round 13
// baseline (378.991 us; speedup 1.0000x reference)
//
#include <hip/hip_runtime.h>
#include <hip/hip_bf16.h>
#include <cstdint>
#include <cstddef>

// Problem constants
#define NTOK 49
#define DIM 384
#define KDIM 384
#define HEADS 12
#define HD 32
#define BATCH 2048
#define MROWS (BATCH * NTOK)   // 100352 = 392 * 256

typedef unsigned short u16;
typedef __bf16 bf16x8 __attribute__((ext_vector_type(8)));
typedef unsigned short u16x8 __attribute__((ext_vector_type(8)));
typedef float f32x4 __attribute__((ext_vector_type(4)));

__device__ __forceinline__ u16 f2b(float f) {
  union { float f; unsigned u; } v; v.f = f;
  unsigned r = v.u + 0x7fffu + ((v.u >> 16) & 1u);   // RNE bf16
  return (u16)(r >> 16);
}

__device__ __forceinline__ bf16x8 ld_bf8(const u16* p) {
  u16x8 u = *(const u16x8*)p;
  return __builtin_bit_cast(bf16x8, u);
}

__device__ __forceinline__ void gload_lds16(const void* g, void* l) {
  __builtin_amdgcn_global_load_lds(
      (const __attribute__((address_space(1))) unsigned*)g,
      (__attribute__((address_space(3))) unsigned*)l, 16, 0, 0);
}

// ---------------- prep: x/w casts + fused bias+mask table (TRANSPOSED) ------
__global__ __launch_bounds__(256) void k_prep(const float* __restrict__ x,
                                              u16* __restrict__ xb,
                                              const float* __restrict__ qkv_w,
                                              u16* __restrict__ wqkvb,
                                              const float* __restrict__ proj_w,
                                              u16* __restrict__ wprojb,
                                              const float* __restrict__ bias_table,
                                              const float* __restrict__ mask,
                                              const int* __restrict__ rel_idx,
                                              float* __restrict__ rpbm) {
  int blk = blockIdx.x;
  if (blk < 38208) {
    const float* in;
    u16* out;
    int i;
    if (blk < 37632) {
      in = x; out = xb; i = blk * 256 + threadIdx.x;
    } else if (blk < 38064) {
      in = qkv_w; out = wqkvb; i = (blk - 37632) * 256 + threadIdx.x;
    } else {
      in = proj_w; out = wprojb; i = (blk - 38064) * 256 + threadIdx.x;
    }
    float4 v = ((const float4*)in)[i];
    ushort4 o;
    o.x = f2b(v.x); o.y = f2b(v.y); o.z = f2b(v.z); o.w = f2b(v.w);
    ((ushort4*)out)[i] = o;
  } else {
    int idx = (blk - 38208) * 256 + threadIdx.x;   // 12*64*4096 entries
    int r  = idx & 3;
    int l  = (idx >> 2) & 63;
    int ni = (idx >> 8) & 3;
    int mi = (idx >> 10) & 3;
    int w  = (idx >> 12) & 63;
    int h  = idx >> 18;
    int kk = mi * 16 + (l >> 4) * 4 + r;   // frag row = k-token
    int qq = ni * 16 + (l & 15);           // frag col = q-token
    float v = -1e30f;
    if (kk < NTOK && qq < NTOK)
      v = bias_table[rel_idx[qq * NTOK + kk] * HEADS + h] +
          mask[(w * NTOK + qq) * NTOK + kk];
    rpbm[idx] = v;
  }
}

// ------- NT GEMM, m201-style 4-phase/K-tile: 256x128, BK=64, 2x48KB dbuf ----
// Per K-tile t (buf=t&1): 4 phases, each {ds_read quad frags; issue 2 stage
// loads (tile t+1); barrier; lgkm(0); setprio+8 MFMA; barrier}. vmcnt(2) once
// per K-tile at phase 0 (2 loads of stage(t+1) stay in flight). K=384 = 6
// K-tiles. T2 swizzle: linear LDS dest, global source seg'=(l&7)^(l>>3),
// read slot = kcol ^ (row&7) (rows 128B wide, 8 slots of 16B).
template <int OUT_BF16, int NCOLS, int NTN, int GD8>
__global__ __launch_bounds__(512, 2) void k_gemm8p(const u16* __restrict__ A,
                                                   const u16* __restrict__ B,
                                                   const float* __restrict__ bias,
                                                   void* __restrict__ Cv) {
  __shared__ u16 sh[49152];   // 96 KB: 2 x (A 256x64 = 32KB + B 128x64 = 16KB)
  int bid = blockIdx.x;
  int tile = (bid & 7) * GD8 + (bid >> 3);   // XCD-contiguous (grid % 8 == 0)
  int mt = tile / NTN, nt = tile - mt * NTN;
  long m0 = (long)mt * 256;
  int n0 = nt * 128;
  int tid = threadIdx.x;
  int lane = tid & 63, wid = tid >> 6;           // 8 waves
  int wr = (wid >> 1) * 64, wc = (wid & 1) * 64; // 4M x 2N wave grid
  int c = lane & 15, g = lane >> 4;
  int r8 = lane >> 3;
  int sg = ((lane & 7) ^ r8) * 8;                // pre-swizzled global col seg
  const u16* gAb = A + (m0 + r8) * (long)KDIM + sg;
  const u16* gBb = B + (long)(n0 + r8) * KDIM + sg;
  int a_l0 = wid * 32;                           // this wave's A stage rows
  int b_l0 = wid * 16;                           // this wave's B stage rows

  f32x4 acc[4][4] = {};

  // one wave-instr: stage 8 rows x 64 cols (1KB), linear LDS dest
#define STA(BUF, KT, Q)                                                        \
  gload_lds16(gAb + (long)(a_l0 + (Q) * 8) * KDIM + (KT),                      \
              &sh[(BUF) * 24576 + (a_l0 + (Q) * 8) * 64] + lane * 8);
#define STB(BUF, KT, Q)                                                        \
  gload_lds16(gBb + (long)(b_l0 + (Q) * 8) * KDIM + (KT),                      \
              &sh[(BUF) * 24576 + 16384 + (b_l0 + (Q) * 8) * 64] + lane * 8);

#define READQ(BUF, MI0, NI0)                                                   \
  const u16* As = sh + (BUF) * 24576;                                          \
  const u16* Bs = As + 16384;                                                  \
  bf16x8 aq[2][2], bq[2][2];                                                   \
  _Pragma("unroll") for (int i = 0; i < 2; ++i) {                              \
    int R = wr + ((MI0) + i) * 16 + c;                                         \
    int S = wc + ((NI0) + i) * 16 + c;                                         \
    _Pragma("unroll") for (int kk = 0; kk < 2; ++kk) {                         \
      aq[i][kk] = ld_bf8(&As[R * 64 + (((kk * 4 + g) ^ (R & 7)) * 8)]);        \
      bq[i][kk] = ld_bf8(&Bs[S * 64 + (((kk * 4 + g) ^ (S & 7)) * 8)]);        \
    }                                                                          \
  }

#define MFMAQ(MI0, NI0)                                                        \
  __builtin_amdgcn_s_setprio(1);                                               \
  _Pragma("unroll") for (int kk = 0; kk < 2; ++kk)                             \
  _Pragma("unroll") for (int i = 0; i < 2; ++i)                                \
  _Pragma("unroll") for (int jj = 0; jj < 2; ++jj)                             \
    acc[(MI0) + i][(NI0) + jj] = __builtin_amdgcn_mfma_f32_16x16x32_bf16(      \
        aq[i][kk], bq[jj][kk], acc[(MI0) + i][(NI0) + jj], 0, 0, 0);           \
  __builtin_amdgcn_s_setprio(0);

  // phase 0: stage issue -> vmcnt -> barrier -> read quad(0,0) -> lgkm -> MFMA
#define GK(T, NV)                                                              \
  {                                                                            \
    if ((T) + 1 < 6) { STA(((T) + 1) & 1, ((T) + 1) * 64, 0)                   \
                       STA(((T) + 1) & 1, ((T) + 1) * 64, 1) }                 \
    asm volatile("s_waitcnt vmcnt(" #NV ")" ::: "memory");                     \
    __builtin_amdgcn_s_barrier();                                              \
    __builtin_amdgcn_sched_barrier(0);                                         \
    { READQ((T) & 1, 0, 0)                                                     \
      asm volatile("s_waitcnt lgkmcnt(0)" ::: "memory");                       \
      __builtin_amdgcn_sched_barrier(0);                                       \
      MFMAQ(0, 0) }                                                            \
    __builtin_amdgcn_s_barrier();                                              \
    { READQ((T) & 1, 2, 0)                                                     \
      if ((T) + 1 < 6) { STA(((T) + 1) & 1, ((T) + 1) * 64, 2)                 \
                         STA(((T) + 1) & 1, ((T) + 1) * 64, 3) }               \
      __builtin_amdgcn_s_barrier();                                            \
      asm volatile("s_waitcnt lgkmcnt(0)" ::: "memory");                       \
      __builtin_amdgcn_sched_barrier(0);                                       \
      MFMAQ(2, 0) }                                                            \
    __builtin_amdgcn_s_barrier();                                              \
    { READQ((T) & 1, 0, 2)                                                     \
      if ((T) + 1 < 6) { STB(((T) + 1) & 1, ((T) + 1) * 64, 0)                 \
                         STB(((T) + 1) & 1, ((T) + 1) * 64, 1) }               \
      __builtin_amdgcn_s_barrier();                                            \
      asm volatile("s_waitcnt lgkmcnt(0)" ::: "memory");                       \
      __builtin_amdgcn_sched_barrier(0);                                       \
      MFMAQ(0, 2) }                                                            \
    __builtin_amdgcn_s_barrier();                                              \
    { READQ((T) & 1, 2, 2)                                                     \
      __builtin_amdgcn_s_barrier();                                            \
      asm volatile("s_waitcnt lgkmcnt(0)" ::: "memory");                       \
      __builtin_amdgcn_sched_barrier(0);                                       \
      MFMAQ(2, 2) }                                                            \
    __builtin_amdgcn_s_barrier();                                              \
  }

  // prologue: stage K-tile 0 fully (6 loads/thread-wave)
  STA(0, 0, 0) STA(0, 0, 1) STA(0, 0, 2) STA(0, 0, 3)
  STB(0, 0, 0) STB(0, 0, 1)

  GK(0, 2) GK(1, 2) GK(2, 2) GK(3, 2) GK(4, 2) GK(5, 0)
#undef GK
#undef MFMAQ
#undef READQ
#undef STB
#undef STA

  // ---- epilogue: LDS transit -> coalesced stores (LDS reuse is safe: all
  // waves' final reads/MFMAs retired before the last barrier) ----
  if (OUT_BF16) {
    u16* C = (u16*)Cv;
#pragma unroll
    for (int mi = 0; mi < 4; ++mi)
#pragma unroll
      for (int ni = 0; ni < 4; ++ni) {
        int col = wc + ni * 16 + c;
        float bv = bias[n0 + col];
#pragma unroll
        for (int r = 0; r < 4; ++r) {
          int row = wr + mi * 16 + g * 4 + r;       // 0..255
          sh[row * 128 + col] = f2b(acc[mi][ni][r] + bv);
        }
      }
    __syncthreads();
#pragma unroll
    for (int rep = 0; rep < 8; ++rep) {
      int idx = rep * 4096 + tid * 8;      // u16 units; 32768 total
      int row = idx >> 7, col = idx & 127;
      *(u16x8*)(C + (m0 + row) * NCOLS + n0 + col) = *(const u16x8*)&sh[idx];
    }
  } else {
    float* C = (float*)Cv;
    float* shf = (float*)sh;               // 128 rows x 128 cols f32 = 64 KB
#pragma unroll
    for (int chunk = 0; chunk < 2; ++chunk) {
      __syncthreads();
      if ((wid >> 2) == chunk) {           // waves 0-3 rows 0-127; 4-7 rest
#pragma unroll
        for (int mi = 0; mi < 4; ++mi)
#pragma unroll
          for (int ni = 0; ni < 4; ++ni) {
            int col = wc + ni * 16 + c;
            float bv = bias[n0 + col];
#pragma unroll
            for (int r = 0; r < 4; ++r) {
              int lr = ((wid >> 1) & 1) * 64 + mi * 16 + g * 4 + r;
              shf[lr * 128 + col] = acc[mi][ni][r] + bv;
            }
          }
      }
      __syncthreads();
#pragma unroll
      for (int rep = 0; rep < 8; ++rep) {
        int idx = rep * 2048 + tid * 4;
        int row = idx >> 7, col = idx & 127;
        *(float4*)(C + (m0 + chunk * 128 + row) * NCOLS + n0 + col) =
            *(const float4*)&shf[idx];
      }
    }
  }
}

// -------- fused window attention, SWAPPED operands (round-11, verified) -----
__global__ __launch_bounds__(256) void k_attn(const u16* __restrict__ qkv,
                                              const float* __restrict__ rpbmT,
                                              u16* __restrict__ attnout) {
  __shared__ u16 P_lds[4][64 * 64];    // P[q][k] bf16, byte ^= (q&7)<<4
  __shared__ u16 vT_lds[4][32 * 64];
  int lane = threadIdx.x & 63, wid = threadIdx.x >> 6;
  int blk = blockIdx.x;                  // w-major remap for rpbmT L2 reuse
  int w = blk / 96;
  int rr = blk - w * 96;
  int j = rr / 3;
  int hb = rr - j * 3;
  int b = j * 64 + w;
  int h = hb * 4 + wid;
  const u16* base = qkv + (size_t)b * (NTOK * 1152);
  int c = lane & 15, g = lane >> 4;

  u16* vt = vT_lds[wid];
  {
    const u16* vbase = base + 2 * DIM + h * HD;
#pragma unroll
    for (int t = 0; t < 4; ++t) {
      int idx = t * 64 + lane;
      int jj = idx >> 2, d0 = (idx & 3) * 8;
      int jr = jj < NTOK ? jj : NTOK - 1;
      u16x8 vv = *(const u16x8*)(vbase + (size_t)jr * 1152 + d0);
#pragma unroll
      for (int dd = 0; dd < 8; ++dd) {
        int d = d0 + dd;
        int byte = (d * 128 + jj * 2) ^ ((d & 7) << 4);
        *(u16*)((char*)vt + byte) = (u16)vv[dd];
      }
    }
  }

  bf16x8 kf[4], qf[4];
#pragma unroll
  for (int mi = 0; mi < 4; ++mi) {
    int row = mi * 16 + c; if (row > NTOK - 1) row = NTOK - 1;
    kf[mi] = ld_bf8(base + (size_t)row * 1152 + DIM + h * HD + g * 8);
  }
#pragma unroll
  for (int nj = 0; nj < 4; ++nj) {
    int row = nj * 16 + c; if (row > NTOK - 1) row = NTOK - 1;
    qf[nj] = ld_bf8(base + (size_t)row * 1152 + h * HD + g * 8);
  }

  f32x4 s[4][4];
  f32x4 zf = {0.f, 0.f, 0.f, 0.f};
#pragma unroll
  for (int mi = 0; mi < 4; ++mi)
#pragma unroll
    for (int nj = 0; nj < 4; ++nj)
      s[mi][nj] = __builtin_amdgcn_mfma_f32_16x16x32_bf16(kf[mi], qf[nj], zf,
                                                          0, 0, 0);

  const float scale = 0.17677669529663687f;   // 32^-0.5
  const f32x4* rp = (const f32x4*)(rpbmT + ((size_t)(h * 64 + w)) * 4096);
#pragma unroll
  for (int mi = 0; mi < 4; ++mi)
#pragma unroll
    for (int nj = 0; nj < 4; ++nj) {
      f32x4 rv = rp[(mi * 4 + nj) * 64 + lane];
#pragma unroll
      for (int r = 0; r < 4; ++r)
        s[mi][nj][r] = s[mi][nj][r] * scale + rv[r];
    }

  float inv[4];
#pragma unroll
  for (int nj = 0; nj < 4; ++nj) {
    float mx = s[0][nj][0];
#pragma unroll
    for (int mi = 0; mi < 4; ++mi)
#pragma unroll
      for (int r = 0; r < 4; ++r)
        mx = fmaxf(mx, s[mi][nj][r]);
    mx = fmaxf(mx, __shfl_xor(mx, 16));
    mx = fmaxf(mx, __shfl_xor(mx, 32));
    float sum = 0.f;
#pragma unroll
    for (int mi = 0; mi < 4; ++mi)
#pragma unroll
      for (int r = 0; r < 4; ++r) {
        float p = __expf(s[mi][nj][r] - mx);
        s[mi][nj][r] = p;
        sum += p;
      }
    sum += __shfl_xor(sum, 16);
    sum += __shfl_xor(sum, 32);
    inv[nj] = __builtin_amdgcn_rcpf(sum);
  }

  u16* pl = P_lds[wid];
#pragma unroll
  for (int mi = 0; mi < 4; ++mi)
#pragma unroll
    for (int nj = 0; nj < 4; ++nj) {
      unsigned w0, w1;
      asm("v_cvt_pk_bf16_f32 %0, %1, %2"
          : "=v"(w0) : "v"(s[mi][nj][0]), "v"(s[mi][nj][1]));
      asm("v_cvt_pk_bf16_f32 %0, %1, %2"
          : "=v"(w1) : "v"(s[mi][nj][2]), "v"(s[mi][nj][3]));
      int q = nj * 16 + c;
      int byte = (q * 128 + (mi * 16 + g * 4) * 2) ^ ((c & 7) << 4);
      uint2 val; val.x = w0; val.y = w1;
      *(uint2*)((char*)pl + byte) = val;
    }
  asm volatile("s_waitcnt lgkmcnt(0)" ::: "memory");
  __builtin_amdgcn_sched_barrier(0);

  f32x4 o[2][4] = {};
#pragma unroll
  for (int ks = 0; ks < 2; ++ks) {
    bf16x8 vb[2];
#pragma unroll
    for (int mi2 = 0; mi2 < 2; ++mi2) {
      int d = mi2 * 16 + c;
      int byte = (d * 128 + ks * 64 + g * 16) ^ ((d & 7) << 4);
      vb[mi2] = __builtin_bit_cast(bf16x8, *(const u16x8*)((const char*)vt + byte));
    }
#pragma unroll
    for (int nj = 0; nj < 4; ++nj) {
      int q = nj * 16 + c;
      int byte = (q * 128 + (ks * 32 + g * 8) * 2) ^ ((c & 7) << 4);
      bf16x8 pb = __builtin_bit_cast(bf16x8, *(const u16x8*)((const char*)pl + byte));
#pragma unroll
      for (int mi2 = 0; mi2 < 2; ++mi2)
        o[mi2][nj] = __builtin_amdgcn_mfma_f32_16x16x32_bf16(vb[mi2], pb,
                                                             o[mi2][nj], 0, 0, 0);
    }
  }

  u16* obase = attnout + (size_t)b * (NTOK * DIM) + h * HD;
#pragma unroll
  for (int mi2 = 0; mi2 < 2; ++mi2)
#pragma unroll
    for (int nj = 0; nj < 4; ++nj) {
      int q = nj * 16 + c;
      if (q < NTOK) {
#pragma unroll
        for (int r = 0; r < 4; ++r)
          obase[(size_t)q * DIM + mi2 * 16 + g * 4 + r] =
              f2b(o[mi2][nj][r] * inv[nj]);
      }
    }
}

// ---------------------------------------------------------------------------
extern "C" void kernel_launch(void* const* d_in, const int* in_sizes, int n_in,
                              void* d_out, int out_size, void* d_ws, size_t ws_size,
                              hipStream_t stream) {
  const float* x       = (const float*)d_in[0];
  const float* qkv_w   = (const float*)d_in[1];
  const float* qkv_b   = (const float*)d_in[2];
  const float* proj_w  = (const float*)d_in[3];
  const float* proj_b  = (const float*)d_in[4];
  const float* bias_tb = (const float*)d_in[5];
  const float* mask    = (const float*)d_in[6];
  const int*   rel_idx = (const int*)d_in[7];
  float* out = (float*)d_out;

  char* ws = (char*)d_ws;
  u16*   xb      = (u16*)(ws + 0);                  //  77,070,336  x bf16
  u16*   wqkvb   = (u16*)(ws + 77070336);           //     884,736  qkv_w bf16
  u16*   wprojb  = (u16*)(ws + 77955072);           //     294,912  proj_w bf16
  float* rpbm    = (float*)(ws + 78249984);         //  12,582,912  bias+mask^T
  u16*   qkv     = (u16*)(ws + 90832896);           // 231,211,008  qkv bf16
  u16*   attnout = (u16*)(ws + 322043904);          //  77,070,336  attn out bf16

  // 1) prep: all casts + transposed bias+mask table
  k_prep<<<50496, 256, 0, stream>>>(x, xb, qkv_w, wqkvb, proj_w, wprojb,
                                    bias_tb, mask, rel_idx, rpbm);

  // 2) QKV GEMM (4-phase/K-tile, BK=64): [100352,384] x [1152,384]^T -> bf16
  k_gemm8p<1, 1152, 9, 441><<<3528, 512, 0, stream>>>(xb, wqkvb, qkv_b,
                                                      (void*)qkv);

  // 3) window attention (swapped-operand) -> bf16 [100352,384]
  k_attn<<<6144, 256, 0, stream>>>(qkv, rpbm, attnout);

  // 4) proj GEMM (4-phase/K-tile): [100352,384] x [384,384]^T -> f32 d_out
  k_gemm8p<0, 384, 3, 147><<<1176, 512, 0, stream>>>(attnout, wprojb, proj_b,
                                                     (void*)out);

  (void)in_sizes; (void)n_in; (void)out_size; (void)ws_size;
}

// Round 14
// 339.589 us; speedup vs baseline: 1.1160x; 1.1160x over previous
//
#include <hip/hip_runtime.h>
#include <hip/hip_bf16.h>
#include <cstdint>
#include <cstddef>

// Problem constants
#define NTOK 49
#define DIM 384
#define KDIM 384
#define HEADS 12
#define HD 32
#define BATCH 2048
#define MROWS (BATCH * NTOK)   // 100352 = 392 * 256

typedef unsigned short u16;
typedef __bf16 bf16x8 __attribute__((ext_vector_type(8)));
typedef unsigned short u16x8 __attribute__((ext_vector_type(8)));
typedef float f32x4 __attribute__((ext_vector_type(4)));

__device__ __forceinline__ u16 f2b(float f) {
  union { float f; unsigned u; } v; v.f = f;
  unsigned r = v.u + 0x7fffu + ((v.u >> 16) & 1u);   // RNE bf16
  return (u16)(r >> 16);
}

__device__ __forceinline__ bf16x8 ld_bf8(const u16* p) {
  u16x8 u = *(const u16x8*)p;
  return __builtin_bit_cast(bf16x8, u);
}

__device__ __forceinline__ void gload_lds16(const void* g, void* l) {
  __builtin_amdgcn_global_load_lds(
      (const __attribute__((address_space(1))) unsigned*)g,
      (__attribute__((address_space(3))) unsigned*)l, 16, 0, 0);
}

// ---------------- prep: x/w casts + fused bias+mask table (TRANSPOSED) ------
__global__ __launch_bounds__(256) void k_prep(const float* __restrict__ x,
                                              u16* __restrict__ xb,
                                              const float* __restrict__ qkv_w,
                                              u16* __restrict__ wqkvb,
                                              const float* __restrict__ proj_w,
                                              u16* __restrict__ wprojb,
                                              const float* __restrict__ bias_table,
                                              const float* __restrict__ mask,
                                              const int* __restrict__ rel_idx,
                                              float* __restrict__ rpbm) {
  int blk = blockIdx.x;
  if (blk < 38208) {
    const float* in;
    u16* out;
    int i;
    if (blk < 37632) {
      in = x; out = xb; i = blk * 256 + threadIdx.x;
    } else if (blk < 38064) {
      in = qkv_w; out = wqkvb; i = (blk - 37632) * 256 + threadIdx.x;
    } else {
      in = proj_w; out = wprojb; i = (blk - 38064) * 256 + threadIdx.x;
    }
    float4 v = ((const float4*)in)[i];
    ushort4 o;
    o.x = f2b(v.x); o.y = f2b(v.y); o.z = f2b(v.z); o.w = f2b(v.w);
    ((ushort4*)out)[i] = o;
  } else {
    int idx = (blk - 38208) * 256 + threadIdx.x;   // 12*64*4096 entries
    int r  = idx & 3;
    int l  = (idx >> 2) & 63;
    int ni = (idx >> 8) & 3;
    int mi = (idx >> 10) & 3;
    int w  = (idx >> 12) & 63;
    int h  = idx >> 18;
    int kk = mi * 16 + (l >> 4) * 4 + r;   // frag row = k-token
    int qq = ni * 16 + (l & 15);           // frag col = q-token
    float v = -1e30f;
    if (kk < NTOK && qq < NTOK)
      v = bias_table[rel_idx[qq * NTOK + kk] * HEADS + h] +
          mask[(w * NTOK + qq) * NTOK + kk];
    rpbm[idx] = v;
  }
}

// ------- NT GEMM: 256x128 tile, 512 thr / 8 waves, 3-buf counted vmcnt ------
// Round-11 verified structure. OUT_BF16=1 (QKV): epilogue writes HEAD-MAJOR
// qkv layout [3][12][BATCH][49][32]; OUT_BF16=0 (proj): f32 row-major.
template <int OUT_BF16, int NCOLS, int NTN, int GD8>
__global__ __launch_bounds__(512, 4) void k_gemm256(const u16* __restrict__ A,
                                                    const u16* __restrict__ B,
                                                    const float* __restrict__ bias,
                                                    void* __restrict__ Cv) {
  __shared__ u16 sh[36864];   // 72 KB: 3 x 24 KB; epilogue reuses 64 KB
  int bid = blockIdx.x;
  int tile = (bid & 7) * GD8 + (bid >> 3);   // XCD-contiguous (grid % 8 == 0)
  int mt = tile / NTN, nt = tile - mt * NTN;
  long m0 = (long)mt * 256;
  int n0 = nt * 128;
  int tid = threadIdx.x;
  int lane = tid & 63, wid = tid >> 6;           // 8 waves
  int wr = (wid >> 1) * 64, wc = (wid & 1) * 64; // 4M x 2N wave grid
  int c = lane & 15, g = lane >> 4;
  int gsw = (g ^ ((c >> 1) & 3)) * 8;            // swizzled read segment

  int srow = wid * 16 + (lane >> 2);             // 0..127
  int scol = ((lane & 3) ^ ((lane >> 3) & 3)) * 8;  // pre-swizzled global seg
  const u16* gA = A + (m0 + srow) * (long)KDIM + scol;
  const u16* gB = B + (long)(n0 + srow) * KDIM + scol;
  int lrow = srow, lseg = (lane & 3) * 8;        // linear LDS dest

  f32x4 acc[4][4] = {};
  bf16x8 af[4], bfr[4];

#define STAGE256(BUF, KT)                                                      \
  {                                                                            \
    u16* As_ = sh + (BUF) * 12288;                                             \
    u16* Bs_ = As_ + 8192;                                                     \
    gload_lds16(gA + (KT), &As_[lrow * 32 + lseg]);                            \
    gload_lds16(gA + (KT) + 128L * KDIM, &As_[(lrow + 128) * 32 + lseg]);      \
    gload_lds16(gB + (KT), &Bs_[lrow * 32 + lseg]);                            \
  }

#define FRAGREAD(BUF)                                                          \
  {                                                                            \
    const u16* As = sh + (BUF) * 12288;                                        \
    const u16* Bs = As + 8192;                                                 \
    _Pragma("unroll") for (int i = 0; i < 4; ++i) {                            \
      af[i]  = ld_bf8(&As[(wr + i * 16 + c) * 32 + gsw]);                      \
      bfr[i] = ld_bf8(&Bs[(wc + i * 16 + c) * 32 + gsw]);                      \
    }                                                                          \
  }

#define MFMA_CL                                                                \
  __builtin_amdgcn_s_setprio(1);                                               \
  _Pragma("unroll") for (int mi = 0; mi < 4; ++mi)                             \
  _Pragma("unroll") for (int ni = 0; ni < 4; ++ni)                             \
      acc[mi][ni] = __builtin_amdgcn_mfma_f32_16x16x32_bf16(                   \
          af[mi], bfr[ni], acc[mi][ni], 0, 0, 0);                              \
  __builtin_amdgcn_s_setprio(0);

#define GITER(T, NV)                                                           \
  {                                                                            \
    MFMA_CL;                                                                   \
    asm volatile("s_waitcnt vmcnt(" #NV ")" ::: "memory");                     \
    __builtin_amdgcn_s_barrier();                                              \
    __builtin_amdgcn_sched_barrier(0);                                         \
    if ((T) + 3 < 12) STAGE256((T) % 3, ((T) + 3) * 32);                       \
    FRAGREAD(((T) + 1) % 3);                                                   \
  }

  STAGE256(0, 0);
  STAGE256(1, 32);
  STAGE256(2, 64);
  asm volatile("s_waitcnt vmcnt(6)" ::: "memory");
  __builtin_amdgcn_s_barrier();
  __builtin_amdgcn_sched_barrier(0);
  FRAGREAD(0);

  GITER(0, 3)  GITER(1, 3)  GITER(2, 3)  GITER(3, 3)
  GITER(4, 3)  GITER(5, 3)  GITER(6, 3)  GITER(7, 3)
  GITER(8, 3)  GITER(9, 3)  GITER(10, 0)
  { MFMA_CL; }   // iter 11: pure MFMA
  __builtin_amdgcn_s_barrier();   // tile-11 reads retired before epilogue
#undef GITER
#undef MFMA_CL
#undef FRAGREAD
#undef STAGE256

  if (OUT_BF16) {
    // head-major qkv out: [t][h][b][tok][d] = [3][12][2048][49][32]
    u16* C = (u16*)Cv;
#pragma unroll
    for (int mi = 0; mi < 4; ++mi)
#pragma unroll
      for (int ni = 0; ni < 4; ++ni) {
        int col = wc + ni * 16 + c;
        float bv = bias[n0 + col];
#pragma unroll
        for (int r = 0; r < 4; ++r) {
          int row = wr + mi * 16 + g * 4 + r;       // 0..255
          sh[row * 128 + col] = f2b(acc[mi][ni][r] + bv);
        }
      }
    __syncthreads();
#pragma unroll
    for (int rep = 0; rep < 8; ++rep) {
      int idx = rep * 4096 + tid * 8;      // u16 units; 32768 total
      int row = idx >> 7, col = idx & 127;
      int grow = (int)m0 + row;
      int b = grow / 49, tok = grow - b * 49;     // const-div -> magic mul
      int gcol = n0 + col;
      int t = gcol / 384;
      int hc = gcol - t * 384;
      int h = hc >> 5, d0 = hc & 31;
      size_t off = (((size_t)(t * 12 + h) * BATCH + b) * 49 + tok) * 32 + d0;
      *(u16x8*)(C + off) = *(const u16x8*)&sh[idx];
    }
  } else {
    float* C = (float*)Cv;
    float* shf = (float*)sh;               // 128 rows x 128 cols f32 = 64 KB
#pragma unroll
    for (int chunk = 0; chunk < 2; ++chunk) {
      __syncthreads();
      if ((wid >> 2) == chunk) {
#pragma unroll
        for (int mi = 0; mi < 4; ++mi)
#pragma unroll
          for (int ni = 0; ni < 4; ++ni) {
            int col = wc + ni * 16 + c;
            float bv = bias[n0 + col];
#pragma unroll
            for (int r = 0; r < 4; ++r) {
              int lr = ((wid >> 1) & 1) * 64 + mi * 16 + g * 4 + r;
              shf[lr * 128 + col] = acc[mi][ni][r] + bv;
            }
          }
      }
      __syncthreads();
#pragma unroll
      for (int rep = 0; rep < 8; ++rep) {
        int idx = rep * 2048 + tid * 4;
        int row = idx >> 7, col = idx & 127;
        *(float4*)(C + (m0 + chunk * 128 + row) * NCOLS + n0 + col) =
            *(const float4*)&shf[idx];
      }
    }
  }
}

// -------- fused window attention, SWAPPED operands, head-major qkv ----------
// qkv[t][h][b][tok][32]: wave reads are 1KB-contiguous per instruction.
__global__ __launch_bounds__(256) void k_attn(const u16* __restrict__ qkv,
                                              const float* __restrict__ rpbmT,
                                              u16* __restrict__ attnout) {
  __shared__ u16 P_lds[4][64 * 64];    // P[q][k] bf16, byte ^= (q&7)<<4
  __shared__ u16 vT_lds[4][32 * 64];
  int lane = threadIdx.x & 63, wid = threadIdx.x >> 6;
  int blk = blockIdx.x;                  // w-major remap for rpbmT L2 reuse
  int w = blk / 96;
  int rr = blk - w * 96;
  int j = rr / 3;
  int hb = rr - j * 3;
  int b = j * 64 + w;
  int h = hb * 4 + wid;
  int c = lane & 15, g = lane >> 4;

  const u16* qh = qkv + ((size_t)(h)*BATCH + b) * (49 * 32);
  const u16* kh = qkv + ((size_t)(12 + h) * BATCH + b) * (49 * 32);
  const u16* vh = qkv + ((size_t)(24 + h) * BATCH + b) * (49 * 32);

  // ---- issue all global loads first (dense 1KB/instr) ----
  u16x8 vv[4];
#pragma unroll
  for (int t = 0; t < 4; ++t) {
    int idx = t * 64 + lane;
    int jj = idx >> 2, d0 = (idx & 3) * 8;
    int jr = jj < NTOK ? jj : NTOK - 1;
    vv[t] = *(const u16x8*)(vh + jr * 32 + d0);
  }
  bf16x8 kf[4], qf[4];
#pragma unroll
  for (int mi = 0; mi < 4; ++mi) {
    int row = mi * 16 + c; if (row > NTOK - 1) row = NTOK - 1;
    kf[mi] = ld_bf8(kh + row * 32 + g * 8);
  }
#pragma unroll
  for (int nj = 0; nj < 4; ++nj) {
    int row = nj * 16 + c; if (row > NTOK - 1) row = NTOK - 1;
    qf[nj] = ld_bf8(qh + row * 32 + g * 8);
  }

  // ---- scatter V^T into LDS (swizzled byte ^= (d&7)<<4) ----
  u16* vt = vT_lds[wid];
#pragma unroll
  for (int t = 0; t < 4; ++t) {
    int idx = t * 64 + lane;
    int jj = idx >> 2, d0 = (idx & 3) * 8;
#pragma unroll
    for (int dd = 0; dd < 8; ++dd) {
      int d = d0 + dd;
      int byte = (d * 128 + jj * 2) ^ ((d & 7) << 4);
      *(u16*)((char*)vt + byte) = (u16)vv[t][dd];
    }
  }

  // ---- S^T[k][q] = K Q^T ----
  f32x4 s[4][4];
  f32x4 zf = {0.f, 0.f, 0.f, 0.f};
#pragma unroll
  for (int mi = 0; mi < 4; ++mi)
#pragma unroll
    for (int nj = 0; nj < 4; ++nj)
      s[mi][nj] = __builtin_amdgcn_mfma_f32_16x16x32_bf16(kf[mi], qf[nj], zf,
                                                          0, 0, 0);

  const float scale = 0.17677669529663687f;   // 32^-0.5
  const f32x4* rp = (const f32x4*)(rpbmT + ((size_t)(h * 64 + w)) * 4096);
#pragma unroll
  for (int mi = 0; mi < 4; ++mi)
#pragma unroll
    for (int nj = 0; nj < 4; ++nj) {
      f32x4 rv = rp[(mi * 4 + nj) * 64 + lane];
#pragma unroll
      for (int r = 0; r < 4; ++r)
        s[mi][nj][r] = s[mi][nj][r] * scale + rv[r];
    }

  // ---- softmax over k (per q-column): 16 lane-local + 2 shfls ----
  float inv[4];
#pragma unroll
  for (int nj = 0; nj < 4; ++nj) {
    float mx = s[0][nj][0];
#pragma unroll
    for (int mi = 0; mi < 4; ++mi)
#pragma unroll
      for (int r = 0; r < 4; ++r)
        mx = fmaxf(mx, s[mi][nj][r]);
    mx = fmaxf(mx, __shfl_xor(mx, 16));
    mx = fmaxf(mx, __shfl_xor(mx, 32));
    float sum = 0.f;
#pragma unroll
    for (int mi = 0; mi < 4; ++mi)
#pragma unroll
      for (int r = 0; r < 4; ++r) {
        float p = __expf(s[mi][nj][r] - mx);
        s[mi][nj][r] = p;
        sum += p;
      }
    sum += __shfl_xor(sum, 16);
    sum += __shfl_xor(sum, 32);
    inv[nj] = __builtin_amdgcn_rcpf(sum);
  }

  // ---- P[q][k] -> LDS: cvt_pk pairs, 16 x ds_write_b64, swizzled ----
  u16* pl = P_lds[wid];
#pragma unroll
  for (int mi = 0; mi < 4; ++mi)
#pragma unroll
    for (int nj = 0; nj < 4; ++nj) {
      unsigned w0, w1;
      asm("v_cvt_pk_bf16_f32 %0, %1, %2"
          : "=v"(w0) : "v"(s[mi][nj][0]), "v"(s[mi][nj][1]));
      asm("v_cvt_pk_bf16_f32 %0, %1, %2"
          : "=v"(w1) : "v"(s[mi][nj][2]), "v"(s[mi][nj][3]));
      int q = nj * 16 + c;
      int byte = (q * 128 + (mi * 16 + g * 4) * 2) ^ ((c & 7) << 4);
      uint2 val; val.x = w0; val.y = w1;
      *(uint2*)((char*)pl + byte) = val;
    }
  asm volatile("s_waitcnt lgkmcnt(0)" ::: "memory");
  __builtin_amdgcn_sched_barrier(0);

  // ---- O^T[d][q] = V^T P^T ----
  f32x4 o[2][4] = {};
#pragma unroll
  for (int ks = 0; ks < 2; ++ks) {
    bf16x8 vb[2];
#pragma unroll
    for (int mi2 = 0; mi2 < 2; ++mi2) {
      int d = mi2 * 16 + c;
      int byte = (d * 128 + ks * 64 + g * 16) ^ ((d & 7) << 4);
      vb[mi2] = __builtin_bit_cast(bf16x8, *(const u16x8*)((const char*)vt + byte));
    }
#pragma unroll
    for (int nj = 0; nj < 4; ++nj) {
      int q = nj * 16 + c;
      int byte = (q * 128 + (ks * 32 + g * 8) * 2) ^ ((c & 7) << 4);
      bf16x8 pb = __builtin_bit_cast(bf16x8, *(const u16x8*)((const char*)pl + byte));
#pragma unroll
      for (int mi2 = 0; mi2 < 2; ++mi2)
        o[mi2][nj] = __builtin_amdgcn_mfma_f32_16x16x32_bf16(vb[mi2], pb,
                                                             o[mi2][nj], 0, 0, 0);
    }
  }

  // ---- store O[b, q, h*32 + d] = o * inv[q] (attnout stays row-major) ----
  u16* obase = attnout + (size_t)b * (NTOK * DIM) + h * HD;
#pragma unroll
  for (int mi2 = 0; mi2 < 2; ++mi2)
#pragma unroll
    for (int nj = 0; nj < 4; ++nj) {
      int q = nj * 16 + c;
      if (q < NTOK) {
#pragma unroll
        for (int r = 0; r < 4; ++r)
          obase[(size_t)q * DIM + mi2 * 16 + g * 4 + r] =
              f2b(o[mi2][nj][r] * inv[nj]);
      }
    }
}

// ---------------------------------------------------------------------------
extern "C" void kernel_launch(void* const* d_in, const int* in_sizes, int n_in,
                              void* d_out, int out_size, void* d_ws, size_t ws_size,
                              hipStream_t stream) {
  const float* x       = (const float*)d_in[0];
  const float* qkv_w   = (const float*)d_in[1];
  const float* qkv_b   = (const float*)d_in[2];
  const float* proj_w  = (const float*)d_in[3];
  const float* proj_b  = (const float*)d_in[4];
  const float* bias_tb = (const float*)d_in[5];
  const float* mask    = (const float*)d_in[6];
  const int*   rel_idx = (const int*)d_in[7];
  float* out = (float*)d_out;

  char* ws = (char*)d_ws;
  u16*   xb      = (u16*)(ws + 0);                  //  77,070,336  x bf16
  u16*   wqkvb   = (u16*)(ws + 77070336);           //     884,736  qkv_w bf16
  u16*   wprojb  = (u16*)(ws + 77955072);           //     294,912  proj_w bf16
  float* rpbm    = (float*)(ws + 78249984);         //  12,582,912  bias+mask^T
  u16*   qkv     = (u16*)(ws + 90832896);           // 231,211,008  qkv head-major
  u16*   attnout = (u16*)(ws + 322043904);          //  77,070,336  attn out bf16

  // 1) prep: all casts + transposed bias+mask table
  k_prep<<<50496, 256, 0, stream>>>(x, xb, qkv_w, wqkvb, proj_w, wprojb,
                                    bias_tb, mask, rel_idx, rpbm);

  // 2) QKV GEMM (256x128, 8 waves) -> head-major qkv [3][12][2048][49][32]
  k_gemm256<1, 1152, 9, 441><<<3528, 512, 0, stream>>>(xb, wqkvb, qkv_b,
                                                       (void*)qkv);

  // 3) window attention (swapped-operand, dense reads) -> bf16 [100352,384]
  k_attn<<<6144, 256, 0, stream>>>(qkv, rpbm, attnout);

  // 4) proj GEMM (256x128, 8 waves): [100352,384] x [384,384]^T -> f32 d_out
  k_gemm256<0, 384, 3, 147><<<1176, 512, 0, stream>>>(attnout, wprojb, proj_b,
                                                      (void*)out);

  (void)in_sizes; (void)n_in; (void)out_size; (void)ws_size;
}